// Round 9
// baseline (1739.029 us; speedup 1.0000x reference)
//
#include <hip/hip_runtime.h>
#include <hip/hip_bf16.h>

typedef __attribute__((ext_vector_type(8))) short s16x8;
typedef __attribute__((ext_vector_type(4))) int   i32x4;
typedef __attribute__((ext_vector_type(4))) float f32x4;

#define NCAPS 4608
#define BATCH 128

// async global->LDS helper (16B per lane, wave-uniform LDS dest)
#define GLOAD_LDS16(gp, lp)                                                   \
  __builtin_amdgcn_global_load_lds(                                           \
      (const __attribute__((address_space(1))) void*)(gp),                    \
      (__attribute__((address_space(3))) void*)(lp), 16, 0, 0)

__device__ __forceinline__ float bf2f(short h) {
  union { unsigned u; float f; } cv;
  cv.u = ((unsigned)(unsigned short)h) << 16;
  return cv.f;
}

// ---------------------------------------------------------------------------
// PREP (fused): blocks [0,5184): conv2_w transpose -> bf16 Wt(1024,20736).
// blocks [5184,8256): conv1 into zero-padded Apad.
// ---------------------------------------------------------------------------
__global__ void prep_kernel(const float* __restrict__ W,
                            __hip_bfloat16* __restrict__ Wt,
                            const float* __restrict__ x,
                            const float* __restrict__ w1,
                            const float* __restrict__ bias1,
                            __hip_bfloat16* __restrict__ Apad) {
  __shared__ float smem[64 * 65];
  int bid = blockIdx.x;
  if (bid < 5184) {
    int kt = (bid % 324) * 64;   // k tile (0..20735)
    int ct = (bid / 324) * 64;   // co tile (0..1023)
    for (int i = threadIdx.x; i < 64 * 64; i += 256) {
      int r = i >> 6, c = i & 63;
      smem[r * 65 + c] = W[(size_t)(kt + r) * 1024 + ct + c];
    }
    __syncthreads();
    for (int i = threadIdx.x; i < 64 * 64; i += 256) {
      int r = i >> 6, c = i & 63;
      Wt[(size_t)(ct + r) * 20736 + kt + c] = __float2bfloat16(smem[c * 65 + r]);
    }
  } else {
    int by = bid - 5184;            // b*24 + y
    int b = by / 24, y = by % 24;
    float* patch = smem;            // 288 floats
    for (int i = threadIdx.x; i < 288; i += 256) {
      int r = i >> 5, c = i & 31;
      patch[i] = x[(size_t)b * 1024 + (y + r) * 32 + c];
    }
    __syncthreads();
    int co = threadIdx.x;
    float bv = bias1[co];
    float acc[24];
#pragma unroll
    for (int i = 0; i < 24; i++) acc[i] = bv;
#pragma unroll
    for (int ky = 0; ky < 9; ky++) {
      float row[32];
#pragma unroll
      for (int c = 0; c < 32; c++) row[c] = patch[ky * 32 + c];
#pragma unroll
      for (int kx = 0; kx < 9; kx++) {
        float wv = w1[(ky * 9 + kx) * 256 + co];
#pragma unroll
        for (int xx = 0; xx < 24; xx++) acc[xx] += row[kx + xx] * wv;
      }
    }
    size_t obase = (((size_t)b * 31 + (y + 3)) * 31 + 3) * 256 + co;
#pragma unroll
    for (int xx = 0; xx < 24; xx++)
      Apad[obase + (size_t)xx * 256] = __float2bfloat16(fmaxf(acc[xx], 0.f));
  }
}

// ---------------------------------------------------------------------------
// conv2 implicit GEMM, bf16 MFMA 16x16x32.
// R9: BM=256 x BN=128, 4 waves 2Mx2N -> per-wave 128x64 (8x4 frags).
// LDS-traffic figure Wm/BM+Wn/BN: 8/256 -> 6/256 (LDS-BW was the measured
// 42%-util ceiling); barriers/FLOP halved. Keeps R4's proven skeleton:
// single-buffer LDS (48KB -> 2 blocks/CU TLP), gload_lds staging,
// rule-#21 both-sides chunk-XOR swizzle, 2 barriers/K-step, XCD mapping.
// ---------------------------------------------------------------------------
__global__ __launch_bounds__(256)
void conv2_mfma_kernel(const __hip_bfloat16* __restrict__ Apad,  // [128][31][31][256]
                       const __hip_bfloat16* __restrict__ Wt,    // [1024][20736]
                       const float* __restrict__ bias,
                       __hip_bfloat16* __restrict__ U) {
  __shared__ __align__(16) __hip_bfloat16 As[256 * 64];   // 32 KB
  __shared__ __align__(16) __hip_bfloat16 Bs[128 * 64];   // 16 KB
  int l = blockIdx.x;            // 0..575
  int xcd = l & 7;
  int j = l >> 3;                // 0..71
  int bm = xcd * 9 + (j >> 3);   // 0..71  (9 bm per XCD; A stays L2-warm)
  int bn = j & 7;                // 0..7

  int tid = threadIdx.x;
  int lane = tid & 63, w = tid >> 6;   // 4 waves
  int seg  = lane & 7;                 // 16B chunk within a row's 128B
  int rsub = lane >> 3;                // row&7 of this lane's staged rows
  int sseg = seg ^ rsub;               // pre-swizzled source chunk (rule #21)

  // A staging: 8 loads/thread, load i covers rows 32i + 8w + (lane>>3)
  const __hip_bfloat16* abase[8];
#pragma unroll
  for (int i = 0; i < 8; i++) {
    int r = 32 * i + 8 * w + rsub;         // 0..255
    int m = bm * 256 + r;
    int b = m / 144, rem = m % 144;
    int oy = rem / 12, ox = rem % 12;
    abase[i] = Apad + (((size_t)(b * 31 + oy * 2)) * 31 + ox * 2) * 256 + sseg * 8;
  }
  // B staging: 4 loads/thread, load g covers rows 32g + 8w + (lane>>3)
  const __hip_bfloat16* bbase[4];
#pragma unroll
  for (int g = 0; g < 4; g++) {
    int r = 32 * g + 8 * w + rsub;         // 0..127
    int n = bn * 128 + r;
    bbase[g] = Wt + (size_t)n * 20736 + sseg * 8;
  }

  f32x4 acc[8][4];
#pragma unroll
  for (int mi = 0; mi < 8; mi++)
#pragma unroll
    for (int ni = 0; ni < 4; ni++)
#pragma unroll
      for (int r = 0; r < 4; r++) acc[mi][ni][r] = 0.f;

  int wm = w >> 1, wn = w & 1;    // wave tile: rows wm*128, cols wn*64
  int lrow = lane & 15;
  int lq = lane >> 4;             // which 8-elem chunk within K=32

  for (int pos = 0; pos < 81; pos++) {
    int ky = pos / 9, kx = pos % 9;
    size_t aoff = (size_t)(ky * 31 + kx) * 256;
    size_t boff = (size_t)pos * 256;
#pragma unroll
    for (int ci0 = 0; ci0 < 256; ci0 += 64) {
#pragma unroll
      for (int i = 0; i < 8; i++)
        GLOAD_LDS16(abase[i] + aoff + ci0, &As[(32 * i + 8 * w) * 64]);
#pragma unroll
      for (int g = 0; g < 4; g++)
        GLOAD_LDS16(bbase[g] + boff + ci0, &Bs[(32 * g + 8 * w) * 64]);
      __syncthreads();
#pragma unroll
      for (int ksub = 0; ksub < 2; ksub++) {
        s16x8 af[8], bf[4];
#pragma unroll
        for (int mi = 0; mi < 8; mi++) {
          int row = wm * 128 + mi * 16 + lrow;
          int c = (ksub * 4 + lq) ^ (row & 7);          // swizzled read chunk
          af[mi] = *(const s16x8*)(As + row * 64 + c * 8);
        }
#pragma unroll
        for (int ni = 0; ni < 4; ni++) {
          int row = wn * 64 + ni * 16 + lrow;
          int c = (ksub * 4 + lq) ^ (row & 7);
          bf[ni] = *(const s16x8*)(Bs + row * 64 + c * 8);
        }
#pragma unroll
        for (int mi = 0; mi < 8; mi++)
#pragma unroll
          for (int ni = 0; ni < 4; ni++)
            acc[mi][ni] = __builtin_amdgcn_mfma_f32_16x16x32_bf16(
                af[mi], bf[ni], acc[mi][ni], 0, 0, 0);
      }
      __syncthreads();
    }
  }

  // epilogue: D row = (lane>>4)*4 + reg, col = lane&15  [measured m89/m91]
#pragma unroll
  for (int mi = 0; mi < 8; mi++) {
    int mg = bm * 256 + wm * 128 + mi * 16 + ((lane >> 4) << 2);
#pragma unroll
    for (int ni = 0; ni < 4; ni++) {
      int ng = bn * 128 + wn * 64 + ni * 16 + (lane & 15);
      float bv = bias[ng];
#pragma unroll
      for (int r = 0; r < 4; r++)
        U[(size_t)(mg + r) * 1024 + ng] = __float2bfloat16(acc[mi][ni][r] + bv);
    }
  }
}

// ---------------------------------------------------------------------------
// u_hat[b,n,kd] = sum_p w[n,kd,p] * u[b,n,p]; one block per capsule n.
// ---------------------------------------------------------------------------
__global__ void uhat_kernel(const __hip_bfloat16* __restrict__ u,
                            const float* __restrict__ w,
                            __hip_bfloat16* __restrict__ uhat) {
  int n = blockIdx.x;
  __shared__ float wsm[32 * 33];
  int t = threadIdx.x;
  for (int i = t; i < 1024; i += 256)
    wsm[(i >> 5) * 33 + (i & 31)] = w[(size_t)n * 1024 + i];
  __syncthreads();
  int kd = t & 31, bs = t >> 5;
  float wr[32];
#pragma unroll
  for (int p = 0; p < 32; p++) wr[p] = wsm[kd * 33 + p];
  for (int bp = 0; bp < 16; bp++) {
    int b = bp * 8 + bs;
    size_t off = ((size_t)b * NCAPS + n) * 32 + kd;
    float uval = bf2f(*(const short*)(u + off));
    float acc = 0.f;
#pragma unroll
    for (int p = 0; p < 32; p++) acc += wr[p] * __shfl(uval, p, 32);
    uhat[off] = __float2bfloat16(acc);
  }
}

// ---------------------------------------------------------------------------
// MEGA: routing (3 iters) + squash + masked decoder, ONE kernel.
// grid = 128 (one block per batch b), block = 512 threads (8 waves).
// ---------------------------------------------------------------------------
__global__ __launch_bounds__(512)
void routing_decoder_kernel(const __hip_bfloat16* __restrict__ uhat,
                            const float* __restrict__ y,
                            const float* __restrict__ d1_w,
                            const float* __restrict__ d1_b,
                            const float* __restrict__ d2_w,
                            const float* __restrict__ d2_b,
                            const float* __restrict__ d3_w,
                            const float* __restrict__ d3_b,
                            float* __restrict__ out) {
  int b = blockIdx.x;
  int t = threadIdx.x;
  int lane = t & 63, wid = t >> 6;
  __shared__ float vls[32];
  __shared__ float red[8][32];
  __shared__ float vms[32];
  __shared__ float h1s[256];
  __shared__ float h2s[512];
  float a1c0[9], a1c1[9];        // cached logits (register-resident)
  const __hip_bfloat16* ub = uhat + (size_t)b * NCAPS * 32;

  for (int it = 0; it < 3; ++it) {
    float part[32];
#pragma unroll
    for (int d = 0; d < 32; ++d) part[d] = 0.f;
    float v0[16], v1[16];
    if (it > 0) {
#pragma unroll
      for (int d = 0; d < 16; ++d) { v0[d] = vls[d]; v1[d] = vls[16 + d]; }
    }
#pragma unroll
    for (int i = 0; i < 9; ++i) {
      int n = t + 512 * i;
      const s16x8* up8 = (const s16x8*)(ub + (size_t)n * 32);
      float uh[32];
#pragma unroll
      for (int q = 0; q < 4; ++q) {
        s16x8 raw = up8[q];
#pragma unroll
        for (int jj = 0; jj < 8; ++jj) uh[q * 8 + jj] = bf2f(raw[jj]);
      }
      float c0 = 0.5f, c1 = 0.5f;
      if (it > 0) {
        float d0 = 0.f, d1 = 0.f;
#pragma unroll
        for (int d = 0; d < 16; ++d) { d0 += uh[d] * v0[d]; d1 += uh[16 + d] * v1[d]; }
        float b0, b1;
        if (it == 1) { a1c0[i] = d0; a1c1[i] = d1; b0 = d0; b1 = d1; }
        else         { b0 = a1c0[i] + d0; b1 = a1c1[i] + d1; }
        float mx = fmaxf(b0, b1);
        float e0 = __expf(b0 - mx), e1 = __expf(b1 - mx);
        float inv = 1.f / (e0 + e1);
        c0 = e0 * inv; c1 = e1 * inv;
      }
#pragma unroll
      for (int d = 0; d < 16; ++d) {
        part[d]      += c0 * uh[d];
        part[16 + d] += c1 * uh[16 + d];
      }
    }
    // wave butterfly reduce (64 lanes)
#pragma unroll
    for (int m = 1; m < 64; m <<= 1)
#pragma unroll
      for (int d = 0; d < 32; ++d) part[d] += __shfl_xor(part[d], m, 64);
    __syncthreads();               // prior-iter red reads / vls reads done
    if (lane == 0)
#pragma unroll
      for (int d = 0; d < 32; ++d) red[wid][d] = part[d];
    __syncthreads();
    if (t < 32) {
      float sd = 0.f;
#pragma unroll
      for (int w2 = 0; w2 < 8; ++w2) sd += red[w2][t];
      float p = sd * sd;
#pragma unroll
      for (int m = 1; m < 16; m <<= 1) p += __shfl_xor(p, m, 64);  // 16-lane group
      float f = p / (1.f + p) / (sqrtf(p) + 1e-7f);
      vls[t] = sd * f;
    }
    __syncthreads();
  }

  // v output + mask
  if (t < 32) {
    float vv = vls[t];
    out[(size_t)b * 32 + t] = vv;
    vms[t] = y[b * 2 + (t >> 4)] * vv;
  }
  __syncthreads();
  // decoder layer 1: 32 -> 256 relu
  if (t < 256) {
    float acc = d1_b[t];
#pragma unroll
    for (int k = 0; k < 32; ++k) acc += vms[k] * d1_w[k * 256 + t];
    h1s[t] = fmaxf(acc, 0.f);
  }
  __syncthreads();
  // decoder layer 2: 256 -> 512 relu
  {
    float acc = d2_b[t];
    for (int k = 0; k < 256; ++k) acc += h1s[k] * d2_w[k * 512 + t];
    h2s[t] = fmaxf(acc, 0.f);
  }
  __syncthreads();
  // decoder layer 3: 512 -> 1024 sigmoid
  float* rout = out + 4096 + (size_t)b * 1024;
#pragma unroll
  for (int jj = 0; jj < 2; ++jj) {
    int jcol = t + jj * 512;
    float acc = d3_b[jcol];
    for (int k = 0; k < 512; ++k) acc += h2s[k] * d3_w[k * 1024 + jcol];
    rout[jcol] = 1.f / (1.f + __expf(-acc));
  }
}

// ---------------------------------------------------------------------------
extern "C" void kernel_launch(void* const* d_in, const int* in_sizes, int n_in,
                              void* d_out, int out_size, void* d_ws, size_t ws_size,
                              hipStream_t stream) {
  const float* input_x = (const float*)d_in[0];
  const float* y       = (const float*)d_in[1];
  const float* conv1_w = (const float*)d_in[2];
  const float* conv1_b = (const float*)d_in[3];
  const float* conv2_w = (const float*)d_in[4];
  const float* conv2_b = (const float*)d_in[5];
  const float* w_caps  = (const float*)d_in[6];
  const float* d1_w    = (const float*)d_in[7];
  const float* d1_b    = (const float*)d_in[8];
  const float* d2_w    = (const float*)d_in[9];
  const float* d2_b    = (const float*)d_in[10];
  const float* d3_w    = (const float*)d_in[11];
  const float* d3_b    = (const float*)d_in[12];
  float* out = (float*)d_out;

  // workspace carve-up (~181 MB -> fits 256MB L3 across replays)
  char* ws = (char*)d_ws;
  size_t apad_bytes = (size_t)128 * 31 * 31 * 256 * 2;                 // 62.9 MB
  __hip_bfloat16* Apad = (__hip_bfloat16*)ws; ws += (apad_bytes + 255) & ~255ull;
  __hip_bfloat16* Wt   = (__hip_bfloat16*)ws; ws += 42467328;          // 1024*20736 bf16
  __hip_bfloat16* u    = (__hip_bfloat16*)ws; ws += 37748736;          // 128*4608*32 bf16
  __hip_bfloat16* uhat = (__hip_bfloat16*)ws; ws += 37748736;          // 128*4608*32 bf16

  hipMemsetAsync(Apad, 0, apad_bytes, stream);   // zero padding borders
  prep_kernel<<<8256, 256, 0, stream>>>(conv2_w, Wt, input_x, conv1_w,
                                        conv1_b, Apad);
  conv2_mfma_kernel<<<576, 256, 0, stream>>>(Apad, Wt, conv2_b, u);
  uhat_kernel<<<NCAPS, 256, 0, stream>>>(u, w_caps, uhat);
  routing_decoder_kernel<<<128, 512, 0, stream>>>(uhat, y, d1_w, d1_b, d2_w,
                                                  d2_b, d3_w, d3_b, out);
}

// Round 10
// 1347.674 us; speedup vs baseline: 1.2904x; 1.2904x over previous
//
#include <hip/hip_runtime.h>
#include <hip/hip_bf16.h>

typedef __attribute__((ext_vector_type(8))) short s16x8;
typedef __attribute__((ext_vector_type(4))) int   i32x4;
typedef __attribute__((ext_vector_type(4))) float f32x4;

#define NCAPS 4608
#define BATCH 128

// async global->LDS helper (16B per lane, wave-uniform LDS dest)
#define GLOAD_LDS16(gp, lp)                                                   \
  __builtin_amdgcn_global_load_lds(                                           \
      (const __attribute__((address_space(1))) void*)(gp),                    \
      (__attribute__((address_space(3))) void*)(lp), 16, 0, 0)

__device__ __forceinline__ float bf2f(short h) {
  union { unsigned u; float f; } cv;
  cv.u = ((unsigned)(unsigned short)h) << 16;
  return cv.f;
}

// ---------------------------------------------------------------------------
// PREP (fused): blocks [0,5184): conv2_w transpose f32(20736,1024) ->
// bf16 Wt(1024,20736). blocks [5184,8256): conv1 into zero-padded Apad.
// ---------------------------------------------------------------------------
__global__ void prep_kernel(const float* __restrict__ W,
                            __hip_bfloat16* __restrict__ Wt,
                            const float* __restrict__ x,
                            const float* __restrict__ w1,
                            const float* __restrict__ bias1,
                            __hip_bfloat16* __restrict__ Apad) {
  __shared__ float smem[64 * 65];
  int bid = blockIdx.x;
  if (bid < 5184) {
    // ---- transpose_w part ----
    int kt = (bid % 324) * 64;   // k tile (0..20735)
    int ct = (bid / 324) * 64;   // co tile (0..1023)
    for (int i = threadIdx.x; i < 64 * 64; i += 256) {
      int r = i >> 6, c = i & 63;
      smem[r * 65 + c] = W[(size_t)(kt + r) * 1024 + ct + c];
    }
    __syncthreads();
    for (int i = threadIdx.x; i < 64 * 64; i += 256) {
      int r = i >> 6, c = i & 63;
      Wt[(size_t)(ct + r) * 20736 + kt + c] = __float2bfloat16(smem[c * 65 + r]);
    }
  } else {
    // ---- conv1 part: (128,32,32,1)x(9,9,1,256) VALID s1 + bias + relu ----
    int by = bid - 5184;            // b*24 + y
    int b = by / 24, y = by % 24;
    float* patch = smem;            // 288 floats
    for (int i = threadIdx.x; i < 288; i += 256) {
      int r = i >> 5, c = i & 31;
      patch[i] = x[(size_t)b * 1024 + (y + r) * 32 + c];
    }
    __syncthreads();
    int co = threadIdx.x;
    float bv = bias1[co];
    float acc[24];
#pragma unroll
    for (int i = 0; i < 24; i++) acc[i] = bv;
#pragma unroll
    for (int ky = 0; ky < 9; ky++) {
      float row[32];
#pragma unroll
      for (int c = 0; c < 32; c++) row[c] = patch[ky * 32 + c];
#pragma unroll
      for (int kx = 0; kx < 9; kx++) {
        float wv = w1[(ky * 9 + kx) * 256 + co];
#pragma unroll
        for (int xx = 0; xx < 24; xx++) acc[xx] += row[kx + xx] * wv;
      }
    }
    // padded store: [b][y+3][x+3][co]
    size_t obase = (((size_t)b * 31 + (y + 3)) * 31 + 3) * 256 + co;
#pragma unroll
    for (int xx = 0; xx < 24; xx++)
      Apad[obase + (size_t)xx * 256] = __float2bfloat16(fmaxf(acc[xx], 0.f));
  }
}

// ---------------------------------------------------------------------------
// conv2 as implicit GEMM, bf16 MFMA 16x16x32 — R4-EXACT structure, the
// 4x-validated best (R4/R7/R8 ~990us, 765 TF = 87% of the m97-structure
// ceiling; every restructure regressed: R5 dbuf 1231, R6 counted-vmcnt
// 256x128 1270, R9 fat-wave 128x64/wave 1377 — occupancy/pipeline-fill
// losses beat LDS/barrier gains each time). m97 single-buffer 32KB LDS,
// 2 barriers/K-step, ~4 blocks/CU TLP (m114 cross-block hiding), gload_lds
// + rule-#21 both-sides chunk-XOR swizzle (0 conflicts), XCD super-row map
// (FETCH 2.8GB->0.7GB), bf16 U (WRITE halved, footprint < L3).
// ---------------------------------------------------------------------------
__global__ __launch_bounds__(256)
void conv2_mfma_kernel(const __hip_bfloat16* __restrict__ Apad,  // [128][31][31][256]
                       const __hip_bfloat16* __restrict__ Wt,    // [1024][20736]
                       const float* __restrict__ bias,
                       __hip_bfloat16* __restrict__ U) {
  __shared__ __align__(16) __hip_bfloat16 As[128 * 64];
  __shared__ __align__(16) __hip_bfloat16 Bs[128 * 64];
  int l = blockIdx.x;
  int s = l >> 7;                 // super-row 0..8
  int w0 = l & 127;
  int xcd = w0 & 7;
  int j = w0 >> 3;                // 0..15
  int bm = s * 16 + xcd * 2 + (j & 1);   // 0..143
  int bn = j >> 1;                       // 0..7

  int tid = threadIdx.x;
  int lane = tid & 63, w = tid >> 6;
  int seg  = lane & 7;   // 16B segment within a row's 128B (8 bf16)
  int rsub = lane >> 3;  // 0..7  == (row & 7) for this lane's staged row
  int sseg = seg ^ rsub; // pre-swizzled source chunk (rule #21)

  // per-lane global source bases; rows r = w*32 + i*8 + rsub
  const __hip_bfloat16* abase[4];
  const __hip_bfloat16* bbase[4];
#pragma unroll
  for (int i = 0; i < 4; i++) {
    int r = w * 32 + i * 8 + rsub;
    int m = bm * 128 + r;
    int b = m / 144, rem = m % 144;
    int oy = rem / 12, ox = rem % 12;
    abase[i] = Apad + (((size_t)(b * 31 + oy * 2)) * 31 + ox * 2) * 256 + sseg * 8;
    int n = bn * 128 + r;
    bbase[i] = Wt + (size_t)n * 20736 + sseg * 8;
  }

  f32x4 acc[4][4];
#pragma unroll
  for (int mi = 0; mi < 4; mi++)
#pragma unroll
    for (int ni = 0; ni < 4; ni++)
#pragma unroll
      for (int r = 0; r < 4; r++) acc[mi][ni][r] = 0.f;

  int wm = w >> 1, wn = w & 1;
  int lrow = lane & 15;
  int lq = lane >> 4;          // quarter: which 8-elem chunk within K=32

  for (int pos = 0; pos < 81; pos++) {
    int ky = pos / 9, kx = pos % 9;
    size_t aoff = (size_t)(ky * 31 + kx) * 256;
    size_t boff = (size_t)pos * 256;
#pragma unroll
    for (int ci0 = 0; ci0 < 256; ci0 += 64) {
#pragma unroll
      for (int i = 0; i < 4; i++) {
        GLOAD_LDS16(abase[i] + aoff + ci0, &As[(w * 32 + i * 8) * 64]);
        GLOAD_LDS16(bbase[i] + boff + ci0, &Bs[(w * 32 + i * 8) * 64]);
      }
      __syncthreads();
#pragma unroll
      for (int ksub = 0; ksub < 2; ksub++) {
        s16x8 af[4], bf[4];
#pragma unroll
        for (int mi = 0; mi < 4; mi++) {
          int row = wm * 64 + mi * 16 + lrow;
          int c = (ksub * 4 + lq) ^ (row & 7);          // swizzled read chunk
          af[mi] = *(const s16x8*)(As + row * 64 + c * 8);
        }
#pragma unroll
        for (int ni = 0; ni < 4; ni++) {
          int row = wn * 64 + ni * 16 + lrow;
          int c = (ksub * 4 + lq) ^ (row & 7);
          bf[ni] = *(const s16x8*)(Bs + row * 64 + c * 8);
        }
#pragma unroll
        for (int mi = 0; mi < 4; mi++)
#pragma unroll
          for (int ni = 0; ni < 4; ni++)
            acc[mi][ni] = __builtin_amdgcn_mfma_f32_16x16x32_bf16(
                af[mi], bf[ni], acc[mi][ni], 0, 0, 0);
      }
      __syncthreads();
    }
  }

  // epilogue: D row = (lane>>4)*4 + reg, col = lane&15  [measured m89/m91]
#pragma unroll
  for (int mi = 0; mi < 4; mi++) {
    int mg = bm * 128 + wm * 64 + mi * 16 + ((lane >> 4) << 2);
#pragma unroll
    for (int ni = 0; ni < 4; ni++) {
      int ng = bn * 128 + wn * 64 + ni * 16 + (lane & 15);
      float bv = bias[ng];
#pragma unroll
      for (int r = 0; r < 4; r++)
        U[(size_t)(mg + r) * 1024 + ng] = __float2bfloat16(acc[mi][ni][r] + bv);
    }
  }
}

// ---------------------------------------------------------------------------
// u_hat[b,n,kd] = sum_p w[n,kd,p] * u[b,n,p]; one block per capsule n.
// u read as bf16, uhat written bf16.
// ---------------------------------------------------------------------------
__global__ void uhat_kernel(const __hip_bfloat16* __restrict__ u,
                            const float* __restrict__ w,
                            __hip_bfloat16* __restrict__ uhat) {
  int n = blockIdx.x;
  __shared__ float wsm[32 * 33];
  int t = threadIdx.x;
  for (int i = t; i < 1024; i += 256)
    wsm[(i >> 5) * 33 + (i & 31)] = w[(size_t)n * 1024 + i];
  __syncthreads();
  int kd = t & 31, bs = t >> 5;
  float wr[32];
#pragma unroll
  for (int p = 0; p < 32; p++) wr[p] = wsm[kd * 33 + p];
  for (int bp = 0; bp < 16; bp++) {
    int b = bp * 8 + bs;
    size_t off = ((size_t)b * NCAPS + n) * 32 + kd;
    float uval = bf2f(*(const short*)(u + off));
    float acc = 0.f;
#pragma unroll
    for (int p = 0; p < 32; p++) acc += wr[p] * __shfl(uval, p, 32);
    uhat[off] = __float2bfloat16(acc);
  }
}

// ---------------------------------------------------------------------------
// MEGA: routing (3 iters) + squash + masked decoder, ONE kernel.
// grid = 128 (one block per batch b), block = 512 threads (8 waves).
// uhat read as bf16 (s16x8 vector loads, bit-shift convert).
// ---------------------------------------------------------------------------
__global__ __launch_bounds__(512)
void routing_decoder_kernel(const __hip_bfloat16* __restrict__ uhat,
                            const float* __restrict__ y,
                            const float* __restrict__ d1_w,
                            const float* __restrict__ d1_b,
                            const float* __restrict__ d2_w,
                            const float* __restrict__ d2_b,
                            const float* __restrict__ d3_w,
                            const float* __restrict__ d3_b,
                            float* __restrict__ out) {
  int b = blockIdx.x;
  int t = threadIdx.x;
  int lane = t & 63, wid = t >> 6;
  __shared__ float vls[32];
  __shared__ float red[8][32];
  __shared__ float vms[32];
  __shared__ float h1s[256];
  __shared__ float h2s[512];
  float a1c0[9], a1c1[9];        // cached logits (register-resident)
  const __hip_bfloat16* ub = uhat + (size_t)b * NCAPS * 32;

  for (int it = 0; it < 3; ++it) {
    float part[32];
#pragma unroll
    for (int d = 0; d < 32; ++d) part[d] = 0.f;
    float v0[16], v1[16];
    if (it > 0) {
#pragma unroll
      for (int d = 0; d < 16; ++d) { v0[d] = vls[d]; v1[d] = vls[16 + d]; }
    }
#pragma unroll
    for (int i = 0; i < 9; ++i) {
      int n = t + 512 * i;
      const s16x8* up8 = (const s16x8*)(ub + (size_t)n * 32);
      float uh[32];
#pragma unroll
      for (int q = 0; q < 4; ++q) {
        s16x8 raw = up8[q];
#pragma unroll
        for (int jj = 0; jj < 8; ++jj) uh[q * 8 + jj] = bf2f(raw[jj]);
      }
      float c0 = 0.5f, c1 = 0.5f;
      if (it > 0) {
        float d0 = 0.f, d1 = 0.f;
#pragma unroll
        for (int d = 0; d < 16; ++d) { d0 += uh[d] * v0[d]; d1 += uh[16 + d] * v1[d]; }
        float b0, b1;
        if (it == 1) { a1c0[i] = d0; a1c1[i] = d1; b0 = d0; b1 = d1; }
        else         { b0 = a1c0[i] + d0; b1 = a1c1[i] + d1; }
        float mx = fmaxf(b0, b1);
        float e0 = __expf(b0 - mx), e1 = __expf(b1 - mx);
        float inv = 1.f / (e0 + e1);
        c0 = e0 * inv; c1 = e1 * inv;
      }
#pragma unroll
      for (int d = 0; d < 16; ++d) {
        part[d]      += c0 * uh[d];
        part[16 + d] += c1 * uh[16 + d];
      }
    }
    // wave butterfly reduce (64 lanes)
#pragma unroll
    for (int m = 1; m < 64; m <<= 1)
#pragma unroll
      for (int d = 0; d < 32; ++d) part[d] += __shfl_xor(part[d], m, 64);
    __syncthreads();               // prior-iter red reads / vls reads done
    if (lane == 0)
#pragma unroll
      for (int d = 0; d < 32; ++d) red[wid][d] = part[d];
    __syncthreads();
    if (t < 32) {
      float sd = 0.f;
#pragma unroll
      for (int w2 = 0; w2 < 8; ++w2) sd += red[w2][t];
      float p = sd * sd;
#pragma unroll
      for (int m = 1; m < 16; m <<= 1) p += __shfl_xor(p, m, 64);  // 16-lane group
      float f = p / (1.f + p) / (sqrtf(p) + 1e-7f);
      vls[t] = sd * f;
    }
    __syncthreads();
  }

  // v output + mask
  if (t < 32) {
    float vv = vls[t];
    out[(size_t)b * 32 + t] = vv;
    vms[t] = y[b * 2 + (t >> 4)] * vv;
  }
  __syncthreads();
  // decoder layer 1: 32 -> 256 relu
  if (t < 256) {
    float acc = d1_b[t];
#pragma unroll
    for (int k = 0; k < 32; ++k) acc += vms[k] * d1_w[k * 256 + t];
    h1s[t] = fmaxf(acc, 0.f);
  }
  __syncthreads();
  // decoder layer 2: 256 -> 512 relu
  {
    float acc = d2_b[t];
    for (int k = 0; k < 256; ++k) acc += h1s[k] * d2_w[k * 512 + t];
    h2s[t] = fmaxf(acc, 0.f);
  }
  __syncthreads();
  // decoder layer 3: 512 -> 1024 sigmoid
  float* rout = out + 4096 + (size_t)b * 1024;
#pragma unroll
  for (int jj = 0; jj < 2; ++jj) {
    int jcol = t + jj * 512;
    float acc = d3_b[jcol];
    for (int k = 0; k < 512; ++k) acc += h2s[k] * d3_w[k * 1024 + jcol];
    rout[jcol] = 1.f / (1.f + __expf(-acc));
  }
}

// ---------------------------------------------------------------------------
extern "C" void kernel_launch(void* const* d_in, const int* in_sizes, int n_in,
                              void* d_out, int out_size, void* d_ws, size_t ws_size,
                              hipStream_t stream) {
  const float* input_x = (const float*)d_in[0];
  const float* y       = (const float*)d_in[1];
  const float* conv1_w = (const float*)d_in[2];
  const float* conv1_b = (const float*)d_in[3];
  const float* conv2_w = (const float*)d_in[4];
  const float* conv2_b = (const float*)d_in[5];
  const float* w_caps  = (const float*)d_in[6];
  const float* d1_w    = (const float*)d_in[7];
  const float* d1_b    = (const float*)d_in[8];
  const float* d2_w    = (const float*)d_in[9];
  const float* d2_b    = (const float*)d_in[10];
  const float* d3_w    = (const float*)d_in[11];
  const float* d3_b    = (const float*)d_in[12];
  float* out = (float*)d_out;

  // workspace carve-up (~181 MB -> fits 256MB L3 across replays)
  char* ws = (char*)d_ws;
  size_t apad_bytes = (size_t)128 * 31 * 31 * 256 * 2;                 // 62.9 MB
  __hip_bfloat16* Apad = (__hip_bfloat16*)ws; ws += (apad_bytes + 255) & ~255ull;
  __hip_bfloat16* Wt   = (__hip_bfloat16*)ws; ws += 42467328;          // 1024*20736 bf16
  __hip_bfloat16* u    = (__hip_bfloat16*)ws; ws += 37748736;          // 128*4608*32 bf16
  __hip_bfloat16* uhat = (__hip_bfloat16*)ws; ws += 37748736;          // 128*4608*32 bf16

  hipMemsetAsync(Apad, 0, apad_bytes, stream);   // zero padding borders
  prep_kernel<<<8256, 256, 0, stream>>>(conv2_w, Wt, input_x, conv1_w,
                                        conv1_b, Apad);
  conv2_mfma_kernel<<<1152, 256, 0, stream>>>(Apad, Wt, conv2_b, u);
  uhat_kernel<<<NCAPS, 256, 0, stream>>>(u, w_caps, uhat);
  routing_decoder_kernel<<<128, 512, 0, stream>>>(uhat, y, d1_w, d1_b, d2_w,
                                                  d2_b, d3_w, d3_b, out);
}

// Round 11
// 1330.980 us; speedup vs baseline: 1.3066x; 1.0125x over previous
//
#include <hip/hip_runtime.h>
#include <hip/hip_bf16.h>

typedef __attribute__((ext_vector_type(8))) short s16x8;
typedef __attribute__((ext_vector_type(4))) int   i32x4;
typedef __attribute__((ext_vector_type(4))) float f32x4;

#define NCAPS 4608
#define BATCH 128

// async global->LDS helper (16B per lane, wave-uniform LDS dest)
#define GLOAD_LDS16(gp, lp)                                                   \
  __builtin_amdgcn_global_load_lds(                                           \
      (const __attribute__((address_space(1))) void*)(gp),                    \
      (__attribute__((address_space(3))) void*)(lp), 16, 0, 0)

__device__ __forceinline__ float bf2f(short h) {
  union { unsigned u; float f; } cv;
  cv.u = ((unsigned)(unsigned short)h) << 16;
  return cv.f;
}

// ---------------------------------------------------------------------------
// PREP (fused): blocks [0,5184): conv2_w transpose f32(20736,1024) ->
// bf16 Wt(1024,20736). blocks [5184,8256): conv1 into zero-padded Apad
// (interior). blocks [8256,8384): zero Apad borders (replaces 63MB memset —
// only 385/961 cells per image are border; saves a dispatch + dep edge).
// ---------------------------------------------------------------------------
__global__ void prep_kernel(const float* __restrict__ W,
                            __hip_bfloat16* __restrict__ Wt,
                            const float* __restrict__ x,
                            const float* __restrict__ w1,
                            const float* __restrict__ bias1,
                            __hip_bfloat16* __restrict__ Apad) {
  __shared__ float smem[64 * 65];
  int bid = blockIdx.x;
  if (bid < 5184) {
    // ---- transpose_w part ----
    int kt = (bid % 324) * 64;   // k tile (0..20735)
    int ct = (bid / 324) * 64;   // co tile (0..1023)
    for (int i = threadIdx.x; i < 64 * 64; i += 256) {
      int r = i >> 6, c = i & 63;
      smem[r * 65 + c] = W[(size_t)(kt + r) * 1024 + ct + c];
    }
    __syncthreads();
    for (int i = threadIdx.x; i < 64 * 64; i += 256) {
      int r = i >> 6, c = i & 63;
      Wt[(size_t)(ct + r) * 20736 + kt + c] = __float2bfloat16(smem[c * 65 + r]);
    }
  } else if (bid < 8256) {
    // ---- conv1 part: (128,32,32,1)x(9,9,1,256) VALID s1 + bias + relu ----
    int by = bid - 5184;            // b*24 + y
    int b = by / 24, y = by % 24;
    float* patch = smem;            // 288 floats
    for (int i = threadIdx.x; i < 288; i += 256) {
      int r = i >> 5, c = i & 31;
      patch[i] = x[(size_t)b * 1024 + (y + r) * 32 + c];
    }
    __syncthreads();
    int co = threadIdx.x;
    float bv = bias1[co];
    float acc[24];
#pragma unroll
    for (int i = 0; i < 24; i++) acc[i] = bv;
#pragma unroll
    for (int ky = 0; ky < 9; ky++) {
      float row[32];
#pragma unroll
      for (int c = 0; c < 32; c++) row[c] = patch[ky * 32 + c];
#pragma unroll
      for (int kx = 0; kx < 9; kx++) {
        float wv = w1[(ky * 9 + kx) * 256 + co];
#pragma unroll
        for (int xx = 0; xx < 24; xx++) acc[xx] += row[kx + xx] * wv;
      }
    }
    // padded store: [b][y+3][x+3][co]
    size_t obase = (((size_t)b * 31 + (y + 3)) * 31 + 3) * 256 + co;
#pragma unroll
    for (int xx = 0; xx < 24; xx++)
      Apad[obase + (size_t)xx * 256] = __float2bfloat16(fmaxf(acc[xx], 0.f));
  } else {
    // ---- border-zero part: one block per batch image ----
    int b = bid - 8256;
    const __hip_bfloat16 z = __float2bfloat16(0.f);
    __hip_bfloat16* base = Apad + (size_t)b * 31 * 31 * 256;
    int t = threadIdx.x;
    // 7 full rows {0,1,2,27,28,29,30} x 31 cols = 217 cells
    const int r7[7] = {0, 1, 2, 27, 28, 29, 30};
#pragma unroll
    for (int ri = 0; ri < 7; ri++) {
      int row = r7[ri];
      for (int col = 0; col < 31; col++)
        base[((size_t)row * 31 + col) * 256 + t] = z;   // coalesced 512B store
    }
    // rows 3..26 x 7 border cols {0,1,2,27,28,29,30} = 168 cells
    for (int row = 3; row < 27; row++) {
#pragma unroll
      for (int ci = 0; ci < 7; ci++) {
        int col = r7[ci];
        base[((size_t)row * 31 + col) * 256 + t] = z;
      }
    }
  }
}

// ---------------------------------------------------------------------------
// conv2 as implicit GEMM, bf16 MFMA 16x16x32 — R4-EXACT structure, the
// 4x-validated best (R4/R7/R8/R10 ~990us, 765 TF = 84-87% of the
// m97-structure ceiling; every restructure regressed: R5 dbuf 1231, R6
// counted-vmcnt 256x128 1270, R9 fat-wave 128x64/wave 1377 —
// occupancy/pipeline-fill losses beat LDS/barrier gains each time).
// m97 single-buffer 32KB LDS, 2 barriers/K-step, ~4 blocks/CU TLP (m114
// cross-block hiding), gload_lds + rule-#21 both-sides chunk-XOR swizzle
// (0 conflicts), XCD super-row map (FETCH 2.8GB->0.7GB), bf16 U.
// ---------------------------------------------------------------------------
__global__ __launch_bounds__(256)
void conv2_mfma_kernel(const __hip_bfloat16* __restrict__ Apad,  // [128][31][31][256]
                       const __hip_bfloat16* __restrict__ Wt,    // [1024][20736]
                       const float* __restrict__ bias,
                       __hip_bfloat16* __restrict__ U) {
  __shared__ __align__(16) __hip_bfloat16 As[128 * 64];
  __shared__ __align__(16) __hip_bfloat16 Bs[128 * 64];
  int l = blockIdx.x;
  int s = l >> 7;                 // super-row 0..8
  int w0 = l & 127;
  int xcd = w0 & 7;
  int j = w0 >> 3;                // 0..15
  int bm = s * 16 + xcd * 2 + (j & 1);   // 0..143
  int bn = j >> 1;                       // 0..7

  int tid = threadIdx.x;
  int lane = tid & 63, w = tid >> 6;
  int seg  = lane & 7;   // 16B segment within a row's 128B (8 bf16)
  int rsub = lane >> 3;  // 0..7  == (row & 7) for this lane's staged row
  int sseg = seg ^ rsub; // pre-swizzled source chunk (rule #21)

  // per-lane global source bases; rows r = w*32 + i*8 + rsub
  const __hip_bfloat16* abase[4];
  const __hip_bfloat16* bbase[4];
#pragma unroll
  for (int i = 0; i < 4; i++) {
    int r = w * 32 + i * 8 + rsub;
    int m = bm * 128 + r;
    int b = m / 144, rem = m % 144;
    int oy = rem / 12, ox = rem % 12;
    abase[i] = Apad + (((size_t)(b * 31 + oy * 2)) * 31 + ox * 2) * 256 + sseg * 8;
    int n = bn * 128 + r;
    bbase[i] = Wt + (size_t)n * 20736 + sseg * 8;
  }

  f32x4 acc[4][4];
#pragma unroll
  for (int mi = 0; mi < 4; mi++)
#pragma unroll
    for (int ni = 0; ni < 4; ni++)
#pragma unroll
      for (int r = 0; r < 4; r++) acc[mi][ni][r] = 0.f;

  int wm = w >> 1, wn = w & 1;
  int lrow = lane & 15;
  int lq = lane >> 4;          // quarter: which 8-elem chunk within K=32

  for (int pos = 0; pos < 81; pos++) {
    int ky = pos / 9, kx = pos % 9;
    size_t aoff = (size_t)(ky * 31 + kx) * 256;
    size_t boff = (size_t)pos * 256;
#pragma unroll
    for (int ci0 = 0; ci0 < 256; ci0 += 64) {
#pragma unroll
      for (int i = 0; i < 4; i++) {
        GLOAD_LDS16(abase[i] + aoff + ci0, &As[(w * 32 + i * 8) * 64]);
        GLOAD_LDS16(bbase[i] + boff + ci0, &Bs[(w * 32 + i * 8) * 64]);
      }
      __syncthreads();
#pragma unroll
      for (int ksub = 0; ksub < 2; ksub++) {
        s16x8 af[4], bf[4];
#pragma unroll
        for (int mi = 0; mi < 4; mi++) {
          int row = wm * 64 + mi * 16 + lrow;
          int c = (ksub * 4 + lq) ^ (row & 7);          // swizzled read chunk
          af[mi] = *(const s16x8*)(As + row * 64 + c * 8);
        }
#pragma unroll
        for (int ni = 0; ni < 4; ni++) {
          int row = wn * 64 + ni * 16 + lrow;
          int c = (ksub * 4 + lq) ^ (row & 7);
          bf[ni] = *(const s16x8*)(Bs + row * 64 + c * 8);
        }
#pragma unroll
        for (int mi = 0; mi < 4; mi++)
#pragma unroll
          for (int ni = 0; ni < 4; ni++)
            acc[mi][ni] = __builtin_amdgcn_mfma_f32_16x16x32_bf16(
                af[mi], bf[ni], acc[mi][ni], 0, 0, 0);
      }
      __syncthreads();
    }
  }

  // epilogue: D row = (lane>>4)*4 + reg, col = lane&15  [measured m89/m91]
#pragma unroll
  for (int mi = 0; mi < 4; mi++) {
    int mg = bm * 128 + wm * 64 + mi * 16 + ((lane >> 4) << 2);
#pragma unroll
    for (int ni = 0; ni < 4; ni++) {
      int ng = bn * 128 + wn * 64 + ni * 16 + (lane & 15);
      float bv = bias[ng];
#pragma unroll
      for (int r = 0; r < 4; r++)
        U[(size_t)(mg + r) * 1024 + ng] = __float2bfloat16(acc[mi][ni][r] + bv);
    }
  }
}

// ---------------------------------------------------------------------------
// u_hat[b,n,kd] = sum_p w[n,kd,p] * u[b,n,p]; one block per capsule n.
// ---------------------------------------------------------------------------
__global__ void uhat_kernel(const __hip_bfloat16* __restrict__ u,
                            const float* __restrict__ w,
                            __hip_bfloat16* __restrict__ uhat) {
  int n = blockIdx.x;
  __shared__ float wsm[32 * 33];
  int t = threadIdx.x;
  for (int i = t; i < 1024; i += 256)
    wsm[(i >> 5) * 33 + (i & 31)] = w[(size_t)n * 1024 + i];
  __syncthreads();
  int kd = t & 31, bs = t >> 5;
  float wr[32];
#pragma unroll
  for (int p = 0; p < 32; p++) wr[p] = wsm[kd * 33 + p];
  for (int bp = 0; bp < 16; bp++) {
    int b = bp * 8 + bs;
    size_t off = ((size_t)b * NCAPS + n) * 32 + kd;
    float uval = bf2f(*(const short*)(u + off));
    float acc = 0.f;
#pragma unroll
    for (int p = 0; p < 32; p++) acc += wr[p] * __shfl(uval, p, 32);
    uhat[off] = __float2bfloat16(acc);
  }
}

// ---------------------------------------------------------------------------
// MEGA: routing (3 iters) + squash + masked decoder, ONE kernel.
// grid = 128 (one block per batch b), block = 512 threads (8 waves).
// ---------------------------------------------------------------------------
__global__ __launch_bounds__(512)
void routing_decoder_kernel(const __hip_bfloat16* __restrict__ uhat,
                            const float* __restrict__ y,
                            const float* __restrict__ d1_w,
                            const float* __restrict__ d1_b,
                            const float* __restrict__ d2_w,
                            const float* __restrict__ d2_b,
                            const float* __restrict__ d3_w,
                            const float* __restrict__ d3_b,
                            float* __restrict__ out) {
  int b = blockIdx.x;
  int t = threadIdx.x;
  int lane = t & 63, wid = t >> 6;
  __shared__ float vls[32];
  __shared__ float red[8][32];
  __shared__ float vms[32];
  __shared__ float h1s[256];
  __shared__ float h2s[512];
  float a1c0[9], a1c1[9];        // cached logits (register-resident)
  const __hip_bfloat16* ub = uhat + (size_t)b * NCAPS * 32;

  for (int it = 0; it < 3; ++it) {
    float part[32];
#pragma unroll
    for (int d = 0; d < 32; ++d) part[d] = 0.f;
    float v0[16], v1[16];
    if (it > 0) {
#pragma unroll
      for (int d = 0; d < 16; ++d) { v0[d] = vls[d]; v1[d] = vls[16 + d]; }
    }
#pragma unroll
    for (int i = 0; i < 9; ++i) {
      int n = t + 512 * i;
      const s16x8* up8 = (const s16x8*)(ub + (size_t)n * 32);
      float uh[32];
#pragma unroll
      for (int q = 0; q < 4; ++q) {
        s16x8 raw = up8[q];
#pragma unroll
        for (int jj = 0; jj < 8; ++jj) uh[q * 8 + jj] = bf2f(raw[jj]);
      }
      float c0 = 0.5f, c1 = 0.5f;
      if (it > 0) {
        float d0 = 0.f, d1 = 0.f;
#pragma unroll
        for (int d = 0; d < 16; ++d) { d0 += uh[d] * v0[d]; d1 += uh[16 + d] * v1[d]; }
        float b0, b1;
        if (it == 1) { a1c0[i] = d0; a1c1[i] = d1; b0 = d0; b1 = d1; }
        else         { b0 = a1c0[i] + d0; b1 = a1c1[i] + d1; }
        float mx = fmaxf(b0, b1);
        float e0 = __expf(b0 - mx), e1 = __expf(b1 - mx);
        float inv = 1.f / (e0 + e1);
        c0 = e0 * inv; c1 = e1 * inv;
      }
#pragma unroll
      for (int d = 0; d < 16; ++d) {
        part[d]      += c0 * uh[d];
        part[16 + d] += c1 * uh[16 + d];
      }
    }
    // wave butterfly reduce (64 lanes)
#pragma unroll
    for (int m = 1; m < 64; m <<= 1)
#pragma unroll
      for (int d = 0; d < 32; ++d) part[d] += __shfl_xor(part[d], m, 64);
    __syncthreads();               // prior-iter red reads / vls reads done
    if (lane == 0)
#pragma unroll
      for (int d = 0; d < 32; ++d) red[wid][d] = part[d];
    __syncthreads();
    if (t < 32) {
      float sd = 0.f;
#pragma unroll
      for (int w2 = 0; w2 < 8; ++w2) sd += red[w2][t];
      float p = sd * sd;
#pragma unroll
      for (int m = 1; m < 16; m <<= 1) p += __shfl_xor(p, m, 64);  // 16-lane group
      float f = p / (1.f + p) / (sqrtf(p) + 1e-7f);
      vls[t] = sd * f;
    }
    __syncthreads();
  }

  // v output + mask
  if (t < 32) {
    float vv = vls[t];
    out[(size_t)b * 32 + t] = vv;
    vms[t] = y[b * 2 + (t >> 4)] * vv;
  }
  __syncthreads();
  // decoder layer 1: 32 -> 256 relu
  if (t < 256) {
    float acc = d1_b[t];
#pragma unroll
    for (int k = 0; k < 32; ++k) acc += vms[k] * d1_w[k * 256 + t];
    h1s[t] = fmaxf(acc, 0.f);
  }
  __syncthreads();
  // decoder layer 2: 256 -> 512 relu
  {
    float acc = d2_b[t];
    for (int k = 0; k < 256; ++k) acc += h1s[k] * d2_w[k * 512 + t];
    h2s[t] = fmaxf(acc, 0.f);
  }
  __syncthreads();
  // decoder layer 3: 512 -> 1024 sigmoid
  float* rout = out + 4096 + (size_t)b * 1024;
#pragma unroll
  for (int jj = 0; jj < 2; ++jj) {
    int jcol = t + jj * 512;
    float acc = d3_b[jcol];
    for (int k = 0; k < 512; ++k) acc += h2s[k] * d3_w[k * 1024 + jcol];
    rout[jcol] = 1.f / (1.f + __expf(-acc));
  }
}

// ---------------------------------------------------------------------------
extern "C" void kernel_launch(void* const* d_in, const int* in_sizes, int n_in,
                              void* d_out, int out_size, void* d_ws, size_t ws_size,
                              hipStream_t stream) {
  const float* input_x = (const float*)d_in[0];
  const float* y       = (const float*)d_in[1];
  const float* conv1_w = (const float*)d_in[2];
  const float* conv1_b = (const float*)d_in[3];
  const float* conv2_w = (const float*)d_in[4];
  const float* conv2_b = (const float*)d_in[5];
  const float* w_caps  = (const float*)d_in[6];
  const float* d1_w    = (const float*)d_in[7];
  const float* d1_b    = (const float*)d_in[8];
  const float* d2_w    = (const float*)d_in[9];
  const float* d2_b    = (const float*)d_in[10];
  const float* d3_w    = (const float*)d_in[11];
  const float* d3_b    = (const float*)d_in[12];
  float* out = (float*)d_out;

  // workspace carve-up (~181 MB -> fits 256MB L3 across replays)
  char* ws = (char*)d_ws;
  size_t apad_bytes = (size_t)128 * 31 * 31 * 256 * 2;                 // 62.9 MB
  __hip_bfloat16* Apad = (__hip_bfloat16*)ws; ws += (apad_bytes + 255) & ~255ull;
  __hip_bfloat16* Wt   = (__hip_bfloat16*)ws; ws += 42467328;          // 1024*20736 bf16
  __hip_bfloat16* u    = (__hip_bfloat16*)ws; ws += 37748736;          // 128*4608*32 bf16
  __hip_bfloat16* uhat = (__hip_bfloat16*)ws; ws += 37748736;          // 128*4608*32 bf16

  prep_kernel<<<8384, 256, 0, stream>>>(conv2_w, Wt, input_x, conv1_w,
                                        conv1_b, Apad);
  conv2_mfma_kernel<<<1152, 256, 0, stream>>>(Apad, Wt, conv2_b, u);
  uhat_kernel<<<NCAPS, 256, 0, stream>>>(u, w_caps, uhat);
  routing_decoder_kernel<<<128, 512, 0, stream>>>(uhat, y, d1_w, d1_b, d2_w,
                                                  d2_b, d3_w, d3_b, out);
}